// Round 12
// baseline (740.191 us; speedup 1.0000x reference)
//
#include <hip/hip_runtime.h>
#include <cstdint>
#include <cstddef>

#define DEVINL __device__ __forceinline__

typedef short s16x8 __attribute__((ext_vector_type(8)));   // 8 bf16 in 4 VGPRs
typedef float f32x4 __attribute__((ext_vector_type(4)));
typedef unsigned short u16x4 __attribute__((ext_vector_type(4)));
typedef unsigned short u16x8 __attribute__((ext_vector_type(8)));

DEVINL unsigned short f2bf(float f) {
  unsigned u = __float_as_uint(f);
  unsigned r = (u + 0x7FFFu + ((u >> 16) & 1u)) >> 16;
  return (unsigned short)r;
}
DEVINL float bf2f(unsigned short b) { return __uint_as_float(((unsigned)b) << 16); }

// async global->LDS, 16B per lane; LDS dest = wave-uniform base + lane*16
DEVINL void gl16(const unsigned short* g, unsigned short* l) {
  __builtin_amdgcn_global_load_lds(
      (const __attribute__((address_space(1))) unsigned int*)g,
      (__attribute__((address_space(3))) unsigned int*)l, 16, 0, 0);
}

__global__ __launch_bounds__(256) void fill_i32(int* __restrict__ p, int val, int n) {
  int i = blockIdx.x * 256 + threadIdx.x;
  if (i < n) p[i] = val;
}

// all 12 weight matrices: W[K,M] fp32 -> Wt hi/lo [M,K] bf16
struct CvtWArgs {
  const float* W[12];
  int K[12];
  int M[12];
};

// R23: prologue mega-kernel — cvt_w_all, fill(cntb), fill(pooled) and
// cvt_split are mutually independent; one block-range-dispatched launch
// replaces 4 (whole blocks per branch, no divergence).
__global__ __launch_bounds__(256) void prologue(
    CvtWArgs a, unsigned short* __restrict__ Wh, unsigned short* __restrict__ Wl,
    const float* __restrict__ xin, unsigned short* __restrict__ Ah,
    unsigned short* __restrict__ Al, int nsplit,
    int* __restrict__ cntb, int ncnt, int* __restrict__ poolz, int npool) {
  int bid = blockIdx.x;
  if (bid < 3072) {
    int tid = bid * 256 + threadIdx.x;
    int mat = tid >> 16;
    int off = tid & 65535;
    if (mat >= 12) return;
    int K = a.K[mat], M = a.M[mat];
    if (off >= K * M) return;
    int k = off / M, m = off - k * M;
    float f = a.W[mat][off];
    unsigned short h = f2bf(f);
    float r = f - bf2f(h);
    size_t dst = (size_t)mat * 65536 + (size_t)m * K + k;
    Wh[dst] = h;
    Wl[dst] = f2bf(r);
  } else if (bid < 3072 + 79) {
    int i = (bid - 3072) * 256 + threadIdx.x;
    if (i < ncnt) cntb[i] = 0;
  } else if (bid < 3200) {
    int i = (bid - 3151) * 256 + threadIdx.x;
    if (i < npool) poolz[i] = 0;
  } else {
    int i = (bid - 3200) * 256 + threadIdx.x;
    if (i >= nsplit) return;
    float f = xin[i];
    unsigned short h = f2bf(f);
    float r = f - bf2f(h);
    Ah[i] = h;
    Al[i] = f2bf(r);
  }
}

// ---------------- LDS-tiled fused 4-matrix MFMA GEMM -------
// R21: staging via __builtin_amdgcn_global_load_lds width=16 (m97/m151
// ladder step).  Linear LDS dest + inverse-XOR-swizzled per-lane GLOBAL
// source + swizzled read (rule #21; XOR is an involution so source-perm ==
// read-perm).  2-barrier loop: issue -> vmcnt(0)+barrier -> compute; no reg
// prefetch (overlap from 3 blocks/CU as in m97).  R14 epilogue, R15 k/v
// de-interleave + XCD swizzle, R20 int2 packing retained.
// obf: 0 = fp32 row, 1 = bf16 row-major (q/k/v).
struct GemmArgs {
  const unsigned short* Wh[4];
  const unsigned short* Wl[4];
  const float* bias[4];
  float* out[4];
  int obf[4];
};

template <int KTOT>   // 192 or 256
__global__ __launch_bounds__(256, 3) void gemm4_lds(
    const unsigned short* __restrict__ Ah, const unsigned short* __restrict__ Al,
    GemmArgs args, int N, int M) {
  const int BK = 64;
  __shared__ unsigned short ash[128 * 64];
  __shared__ unsigned short asl[128 * 64];
  __shared__ unsigned short wsh[64 * 64];
  __shared__ unsigned short wsl[64 * 64];
  int tid = threadIdx.x;
  int wave = tid >> 6, lane = tid & 63;
  int lrow = lane & 15, quad = lane >> 4;
  int mt = M >> 6;
  int ntile = mt * 4;
  // XCD-chunked bijective swizzle: each XCD gets a contiguous run of work
  // ids => complete row-stripes => 16x A-tile reuse happens inside one L2.
  int id = blockIdx.x, nwg = gridDim.x;
  int q8 = nwg >> 3, r8 = nwg & 7;
  int xcd = id & 7, j8 = id >> 3;
  int wg = (xcd < r8 ? xcd * (q8 + 1) : r8 * (q8 + 1) + (xcd - r8) * q8) + j8;
  int by = wg / ntile;
  int bxx = wg - by * ntile;
  int z = bxx / mt;
  int colTile = bxx - z * mt;
  int row0 = by * 128;
  int col0 = colTile * 64;
  const unsigned short* __restrict__ Wh = args.Wh[z];
  const unsigned short* __restrict__ Wl = args.Wl[z];
  const bool full = (args.obf[z] == 0);

  // per-lane source geometry for gload_lds (loop-invariant parts)
  int lr8 = lane >> 3;          // row within 8-row segment
  int kq = lane & 7;            // 16B chunk within row

  f32x4 acc[2][4] = {};

  for (int k0 = 0; k0 < KTOT; k0 += BK) {
    __syncthreads();   // previous step's LDS consumers done
    // A tiles: 16 segments of 1KB each (8 rows x 128B); wave w does s=w+4i
#pragma unroll
    for (int i = 0; i < 4; i++) {
      int s = wave + i * 4;
      int row = s * 8 + lr8;
      int gr = row0 + row; if (gr >= N) gr = N - 1;
      size_t gofs = (size_t)gr * KTOT + k0 + ((kq ^ (row & 7)) * 8);
      gl16(Ah + gofs, ash + s * 512);
      gl16(Al + gofs, asl + s * 512);
    }
    // W tiles: 8 segments
#pragma unroll
    for (int i = 0; i < 2; i++) {
      int s = wave + i * 4;
      int row = s * 8 + lr8;
      size_t gofs = (size_t)(col0 + row) * KTOT + k0 + ((kq ^ (row & 7)) * 8);
      gl16(Wh + gofs, wsh + s * 512);
      if (full) gl16(Wl + gofs, wsl + s * 512);
    }
    asm volatile("s_waitcnt vmcnt(0)" ::: "memory");
    __syncthreads();   // LDS tile visible to all waves
#pragma unroll
    for (int kk = 0; kk < 2; kk++) {
      s16x8 fah[2], fal[2], fbh[4], fbl[4];
#pragma unroll
      for (int rf = 0; rf < 2; rf++) {
        int r = wave * 32 + rf * 16 + lrow;
        int sq = (kk * 4 + quad) ^ (lrow & 7);
        fah[rf] = *(const s16x8*)(ash + r * 64 + sq * 8);
        fal[rf] = *(const s16x8*)(asl + r * 64 + sq * 8);
      }
#pragma unroll
      for (int cf = 0; cf < 4; cf++) {
        int cc = cf * 16 + lrow;
        int sq = (kk * 4 + quad) ^ (lrow & 7);
        fbh[cf] = *(const s16x8*)(wsh + cc * 64 + sq * 8);
        if (full) fbl[cf] = *(const s16x8*)(wsl + cc * 64 + sq * 8);
      }
#pragma unroll
      for (int rf = 0; rf < 2; rf++)
#pragma unroll
        for (int cf = 0; cf < 4; cf++) {
          acc[rf][cf] = __builtin_amdgcn_mfma_f32_16x16x32_bf16(fah[rf], fbh[cf], acc[rf][cf], 0, 0, 0);
          acc[rf][cf] = __builtin_amdgcn_mfma_f32_16x16x32_bf16(fal[rf], fbh[cf], acc[rf][cf], 0, 0, 0);
          if (full)
            acc[rf][cf] = __builtin_amdgcn_mfma_f32_16x16x32_bf16(fah[rf], fbl[cf], acc[rf][cf], 0, 0, 0);
        }
    }
  }
  const float* __restrict__ bias = args.bias[z];
  int obf = args.obf[z];
  if (obf == 0) {
    // fp32 direct stores: each instr covers 4 full 64B lines — already fine
    float* __restrict__ C = args.out[z];
#pragma unroll
    for (int cf = 0; cf < 4; cf++) {
      int col = col0 + cf * 16 + lrow;
      float bv = bias[col];
#pragma unroll
      for (int rf = 0; rf < 2; rf++) {
        int rb = row0 + wave * 32 + rf * 16 + quad * 4;
#pragma unroll
        for (int r = 0; r < 4; r++) {
          int rr = rb + r;
          if (rr < N) C[(size_t)rr * M + col] = acc[rf][cf][r] + bv;
        }
      }
    }
  } else {
    // bf16 row-major: stage u16 tile in ash (free after K-loop), store dense
    __syncthreads();
#pragma unroll
    for (int cf = 0; cf < 4; cf++) {
      int col = cf * 16 + lrow;
      float bv = bias[col0 + col];
#pragma unroll
      for (int rf = 0; rf < 2; rf++) {
        int rl = wave * 32 + rf * 16 + quad * 4;
#pragma unroll
        for (int r = 0; r < 4; r++)
          ash[(rl + r) * 64 + col] = f2bf(acc[rf][cf][r] + bv);
      }
    }
    __syncthreads();
    unsigned short* __restrict__ C = (unsigned short*)args.out[z];
    // row-major M cols, 16B chunks.  1024 chunks / 256 threads.
#pragma unroll
    for (int i = 0; i < 4; i++) {
      int c = tid + i * 256;
      int row = c >> 3, g8 = c & 7;
      int rr = row0 + row;
      if (rr < N)
        *(u16x8*)(C + (size_t)rr * M + col0 + g8 * 8) =
            *(const u16x8*)(ash + row * 64 + g8 * 8);
    }
  }
}

// ---------------- counting sort of edges by dst ----------------

__global__ __launch_bounds__(256) void hist_dst(const int* __restrict__ dst,
                                                int* __restrict__ cnt, int E) {
  int e = blockIdx.x * 256 + threadIdx.x;
  if (e < E) atomicAdd(&cnt[dst[e] + 1], 1);
}

__global__ __launch_bounds__(1024) void scan_hist(const int* __restrict__ cnt,
                                                  int* __restrict__ start,
                                                  int* __restrict__ off, int N) {
  __shared__ int sums[1024];
  const int CH = 20;
  int t = threadIdx.x;
  int base = t * CH;
  int local[CH];
  int tot = 0;
  if (base < N) {
#pragma unroll
    for (int i = 0; i < CH; i++) { local[i] = cnt[base + i]; tot += local[i]; }
  }
  sums[t] = tot;
  __syncthreads();
  for (int d = 1; d < 1024; d <<= 1) {
    int v = (t >= d) ? sums[t - d] : 0;
    __syncthreads();
    sums[t] += v;
    __syncthreads();
  }
  if (base < N) {
    int run = (t == 0) ? 0 : sums[t - 1];
#pragma unroll
    for (int i = 0; i < CH; i++) { start[base + i] = run; off[base + i] = run; run += local[i]; }
    if (base + CH == N) start[N] = run;
  }
}

// R20: {src+1, bits(ea)} packed into one int2 -> 2 stores/edge (one 8B)
// instead of 3 scattered 4B stores; fewer partial-line RMWs on the random
// pos scatter.  eid_s stays separate (read per-lane in alpha writeback).
__global__ __launch_bounds__(256) void scatter_edges(
    const int* __restrict__ src, const int* __restrict__ dst,
    const float* __restrict__ ea, int* __restrict__ off,
    int2* __restrict__ se, int* __restrict__ eid_s, int E) {
  int e = blockIdx.x * 256 + threadIdx.x;
  if (e >= E) return;
  int d = dst[e] + 1;
  int pos = atomicAdd(&off[d], 1);
  se[pos] = make_int2(src[e] + 1, __float_as_int(ea[e]));
  eid_s[pos] = e;
}

// ------- fused per-dst attention.
// R16: 2 edges per wave-step; depth-4 pair pipeline (8 edges in flight);
// cross-half combine via shfl_xor(32).  Attn is at its compulsory-traffic
// floor (157+36)MB / 2.7TB/s — the 8x-XCD k/v replication is invariant for
// dst-parallel order (R22 depth-6 null confirmed).
// R17: MODE 1 fuses LN+ReLU+bf16-split into the epilogue (layers 1,2).
// R24: MODE 0 (layer 3) fuses residual+relu+batch-pooling: the wave holds
// the full 192-ch x3 row at epilogue time -> compute x + relu(x3) and
// atomicAdd into pooled/cnt directly.  Kills the xa write (20.5MB), the
// resid_pool2 re-read (30.7MB) and one launch.  R20: packed int2 preload.
template <int H, int ACT, int MODE>
__global__ __launch_bounds__(256) void attn_fused(
    const unsigned short* __restrict__ q, const unsigned short* __restrict__ kb,
    const unsigned short* __restrict__ vb, const float* __restrict__ We,
    const int* __restrict__ start, const int2* __restrict__ se,
    const int* __restrict__ eid_s,
    float* __restrict__ sc, float* __restrict__ outp,
    float* __restrict__ alpha, int Nn, float scale,
    const float* __restrict__ gam, const float* __restrict__ bet,
    unsigned short* __restrict__ hi, unsigned short* __restrict__ lo,
    const float* __restrict__ xres, const int* __restrict__ batchv,
    float* __restrict__ pooled, float* __restrict__ cntv) {
  const int HC = ACT * 8;
  const int LPH2 = ACT / H;   // lanes per head within a half
  const int D = 4;            // pipeline depth (pairs in flight)
  int w = (blockIdx.x * 256 + threadIdx.x) >> 6;
  int lane = threadIdx.x & 63;
  if (w >= Nn) return;
  int b = start[w], e = start[w + 1];
  int hlane = lane & 31, half = lane >> 5;
  bool act = hlane < ACT;
  int idx = hlane * 8;
  int head = hlane / LPH2;
  float q8[8], We8[8];
#pragma unroll
  for (int j = 0; j < 8; j++) { q8[j] = 0.f; We8[j] = 0.f; }
  if (act) {
    u16x8 qv = *(const u16x8*)(q + (size_t)w * HC + idx);
#pragma unroll
    for (int j = 0; j < 8; j++) q8[j] = bf2f(qv[j]);
    float4 w0 = *(const float4*)(We + idx);
    float4 w1 = *(const float4*)(We + idx + 4);
    We8[0] = w0.x; We8[1] = w0.y; We8[2] = w0.z; We8[3] = w0.w;
    We8[4] = w1.x; We8[5] = w1.y; We8[6] = w1.z; We8[7] = w1.w;
  }
  float qwe = 0.f;
#pragma unroll
  for (int j = 0; j < 8; j++) qwe = fmaf(q8[j], We8[j], qwe);
#pragma unroll
  for (int mm = 1; mm < LPH2; mm <<= 1) qwe += __shfl_xor(qwe, mm, 64);

  float l = 0.f, tv = 0.f;
  float accv[8] = {0.f, 0.f, 0.f, 0.f, 0.f, 0.f, 0.f, 0.f};

  auto step = [&](u16x8 kc, u16x8 vc, float eav, int pairpos) {
    bool vld = (pairpos + half) < e;
    float p = 0.f;
#pragma unroll
    for (int j = 0; j < 8; j++) p = fmaf(q8[j], bf2f(kc[j]), p);
#pragma unroll
    for (int mm = 1; mm < LPH2; mm <<= 1) p += __shfl_xor(p, mm, 64);
    float es = __expf((p + eav * qwe) * scale);
    if (!vld) es = 0.f;
    if (act && vld && (hlane % LPH2) == 0)
      sc[(size_t)(pairpos + half) * H + head] = es;
    l += es;
    tv = fmaf(es, eav, tv);
#pragma unroll
    for (int j = 0; j < 8; j++) accv[j] = fmaf(es, bf2f(vc[j]), accv[j]);
  };

  u16x8 z8 = {0, 0, 0, 0, 0, 0, 0, 0};
  u16x8 kS[D], vS[D];
  float eaS[D];
#pragma unroll
  for (int j = 0; j < D; j++) { kS[j] = z8; vS[j] = z8; eaS[j] = 0.f; }

  auto preload = [&](int pairpos, int st) {
    int pp = pairpos + half;
    int pc = pp < e ? pp : (e - 1);
    int2 pr = se[pc];
    int s = pr.x;
    eaS[st] = __int_as_float(pr.y);
    if (act) {
      kS[st] = *(const u16x8*)(kb + (size_t)s * HC + idx);
      vS[st] = *(const u16x8*)(vb + (size_t)s * HC + idx);
    }
  };

#pragma unroll
  for (int j = 0; j < D; j++) if (b + 2 * j < e) preload(b + 2 * j, j);

  for (int pos = b; pos < e; pos += 2 * D) {
#pragma unroll
    for (int j = 0; j < D; j++) {
      int pp = pos + 2 * j;
      if (pp < e) {
        u16x8 kc = kS[j];
        u16x8 vc = vS[j];
        float ec = eaS[j];
        if (pp + 2 * D < e) preload(pp + 2 * D, j);
        step(kc, vc, ec, pp);
      }
    }
  }

  // combine the two edge-halves
  l += __shfl_xor(l, 32, 64);
  tv += __shfl_xor(tv, 32, 64);
#pragma unroll
  for (int j = 0; j < 8; j++) accv[j] += __shfl_xor(accv[j], 32, 64);

  float invl = 1.0f / (l + 1e-16f);
  if (MODE == 1) {
    // fused LN + relu + bf16 hi/lo split (layers 1,2; ACT==32)
    if (half == 0) {
      const float* orow = outp + (size_t)w * HC + idx;
      float4 o0 = *(const float4*)orow;
      float4 o1 = *(const float4*)(orow + 4);
      float y[8] = {o0.x, o0.y, o0.z, o0.w, o1.x, o1.y, o1.z, o1.w};
#pragma unroll
      for (int j = 0; j < 8; j++) y[j] += (accv[j] + tv * We8[j]) * invl;
      float s = 0.f, s2 = 0.f;
#pragma unroll
      for (int j = 0; j < 8; j++) { s += y[j]; s2 = fmaf(y[j], y[j], s2); }
#pragma unroll
      for (int mm = 1; mm < 32; mm <<= 1) {
        s += __shfl_xor(s, mm, 64);
        s2 += __shfl_xor(s2, mm, 64);
      }
      float mu = s * (1.0f / 256.0f);
      float var = s2 * (1.0f / 256.0f) - mu * mu;
      float rinv = rsqrtf(var + 1e-5f);
      float4 g0 = *(const float4*)(gam + idx);
      float4 g1v = *(const float4*)(gam + idx + 4);
      float4 b0 = *(const float4*)(bet + idx);
      float4 b1 = *(const float4*)(bet + idx + 4);
      float gg[8] = {g0.x, g0.y, g0.z, g0.w, g1v.x, g1v.y, g1v.z, g1v.w};
      float bb[8] = {b0.x, b0.y, b0.z, b0.w, b1.x, b1.y, b1.z, b1.w};
      u16x8 yh, yl;
#pragma unroll
      for (int j = 0; j < 8; j++) {
        float t = fmaxf(fmaf((y[j] - mu) * rinv, gg[j], bb[j]), 0.f);
        unsigned short hh = f2bf(t);
        yh[j] = hh;
        yl[j] = f2bf(t - bf2f(hh));
      }
      *(u16x8*)(hi + (size_t)w * HC + idx) = yh;
      *(u16x8*)(lo + (size_t)w * HC + idx) = yl;
    }
  } else {
    // MODE 0: fused residual + relu + batch pooling (layer 3)
    if (act && half == 0) {
      const float* orow = outp + (size_t)w * HC + idx;
      float4 o0 = *(const float4*)orow;
      float4 o1 = *(const float4*)(orow + 4);
      float y[8] = {o0.x, o0.y, o0.z, o0.w, o1.x, o1.y, o1.z, o1.w};
#pragma unroll
      for (int j = 0; j < 8; j++) y[j] += (accv[j] + tv * We8[j]) * invl;
      const float* xrow = xres + (size_t)w * HC + idx;
      float4 x0 = *(const float4*)xrow;
      float4 x1 = *(const float4*)(xrow + 4);
      float xv[8] = {x0.x, x0.y, x0.z, x0.w, x1.x, x1.y, x1.z, x1.w};
      int bb = batchv[w];
      float* prow = pooled + (size_t)bb * HC + idx;
#pragma unroll
      for (int j = 0; j < 8; j++)
        atomicAdd(&prow[j], xv[j] + fmaxf(y[j], 0.f));
      if (hlane == 0) atomicAdd(&cntv[bb], 1.0f);
    }
  }
  {
    int len = e - b;
    const int PCH = 64 / H;
    int p_of = lane / H;
    int h_of = lane - p_of * H;
    float myinv = __shfl(invl, h_of * LPH2, 64);   // head h_of's denominator
    __threadfence_block();
    for (int base = 0; base < len; base += PCH) {
      int po = base + p_of;
      if (p_of < PCH && po < len) {
        int pos = b + po;
        float es = sc[(size_t)pos * H + h_of];
        alpha[(size_t)eid_s[pos] * H + h_of] = es * myinv;
      }
    }
  }
}

// ---------------- head MLP ----------------

__global__ __launch_bounds__(64) void head_mlp(
    const float* __restrict__ pooled, const float* __restrict__ cnt,
    const float* __restrict__ fc1w, const float* __restrict__ fc1b,
    const float* __restrict__ fc2w, const float* __restrict__ fc2b,
    float* __restrict__ logits) {
  int b = blockIdx.x;
  int t = threadIdx.x;
  __shared__ float p[192];
  __shared__ float hbuf[32];
  float inv = 1.0f / fmaxf(cnt[b], 1.0f);
  for (int i = t; i < 192; i += 64) p[i] = pooled[b * 192 + i] * inv;
  __syncthreads();
  if (t < 32) {
    float acc = fc1b[t];
    for (int i = 0; i < 192; i++) acc = fmaf(p[i], fc1w[i * 32 + t], acc);
    hbuf[t] = fmaxf(acc, 0.f);
  }
  __syncthreads();
  if (t < 2) {
    float acc = fc2b[t];
    for (int j = 0; j < 32; j++) acc = fmaf(hbuf[j], fc2w[j * 2 + t], acc);
    logits[b * 2 + t] = acc;
  }
}

static inline int divup(int a, int b) { return (a + b - 1) / b; }

extern "C" void kernel_launch(void* const* d_in, const int* in_sizes, int n_in,
                              void* d_out, int out_size, void* d_ws, size_t ws_size,
                              hipStream_t stream) {
  const int N = 20000, E = 320000, B = 64;
  const float* x     = (const float*)d_in[0];
  const int*   ei    = (const int*)d_in[1];
  const float* eattr = (const float*)d_in[2];
  const int*   batch = (const int*)d_in[3];
  const int* srcp = ei;
  const int* dstp = ei + E;

  const float* Wq[3]; const float* bq[3]; const float* Wk[3]; const float* bk[3];
  const float* Wv[3]; const float* bv[3]; const float* We[3]; const float* Ws[3];
  const float* bs[3];
  for (int l = 0; l < 3; l++) {
    int base = 4 + l * 9;
    Wq[l] = (const float*)d_in[base + 0]; bq[l] = (const float*)d_in[base + 1];
    Wk[l] = (const float*)d_in[base + 2]; bk[l] = (const float*)d_in[base + 3];
    Wv[l] = (const float*)d_in[base + 4]; bv[l] = (const float*)d_in[base + 5];
    We[l] = (const float*)d_in[base + 6];
    Ws[l] = (const float*)d_in[base + 7]; bs[l] = (const float*)d_in[base + 8];
  }
  const float* g1  = (const float*)d_in[31]; const float* be1 = (const float*)d_in[32];
  const float* g2  = (const float*)d_in[33]; const float* be2 = (const float*)d_in[34];
  const float* fc1w = (const float*)d_in[35]; const float* fc1b = (const float*)d_in[36];
  const float* fc2w = (const float*)d_in[37]; const float* fc2b = (const float*)d_in[38];

  float* out = (float*)d_out;
  float* logits = out;
  float* a1 = out + 128;
  float* a2 = a1 + (size_t)E * 4;
  float* a3 = a2 + (size_t)E * 4;

  float* ws = (float*)d_ws;
  size_t o = 0;
  float* qb = ws + o; o += (size_t)N * 256;   // bf16 q (oversized ok)
  float* kvb = ws + o; o += (size_t)N * 256;  // bf16 k then v (N*256 u16 each)
  float* xa = ws + o; o += (size_t)N * 256;
  float* xb = ws + o; o += (size_t)N * 256;
  float* sc = ws + o; o += (size_t)E * 6;
  int*   cntb  = (int*)(ws + o); o += N;
  int*   startb= (int*)(ws + o); o += N + 1;
  int*   offb  = (int*)(ws + o); o += N + 1;
  int2*  se    = (int2*)(ws + o); o += (size_t)E * 2;   // 8B-aligned (o even)
  int*   eid_s = (int*)(ws + o); o += E;
  float* pooled = ws + o; o += (size_t)B * 192;
  float* cnt    = ws + o; o += B;
  unsigned short* Ah = (unsigned short*)(ws + o); o += (size_t)N * 128;
  unsigned short* Al = (unsigned short*)(ws + o); o += (size_t)N * 128;
  unsigned short* Wh12 = (unsigned short*)(ws + o); o += (size_t)12 * 32768;
  unsigned short* Wl12 = (unsigned short*)(ws + o); o += (size_t)12 * 32768;

  unsigned short* qh = (unsigned short*)qb;
  unsigned short* kh = (unsigned short*)kvb;
  unsigned short* vh = kh + (size_t)N * 256;

  dim3 blk(256);

  struct LayerCfg { int K, M; float scale; };
  LayerCfg cfg[3] = {
    {192, 256, 0.125f},
    {256, 256, 0.125f},
    {256, 192, 0.1767766952966369f},
  };
  CvtWArgs cwa;
  for (int l = 0; l < 3; l++) {
    cwa.W[l * 4 + 0] = Wq[l]; cwa.W[l * 4 + 1] = Wk[l];
    cwa.W[l * 4 + 2] = Wv[l]; cwa.W[l * 4 + 3] = Ws[l];
    for (int zz = 0; zz < 4; zz++) {
      cwa.K[l * 4 + zz] = cfg[l].K; cwa.M[l * 4 + zz] = cfg[l].M;
    }
  }

  // prologue: cvt_w_all + fill(cntb) + fill(pooled+cnt) + cvt_split fused
  prologue<<<3200 + divup(N * 192, 256), blk, 0, stream>>>(
      cwa, Wh12, Wl12, x, Ah, Al, N * 192, cntb, N, (int*)pooled, B * 192 + B);

  hist_dst<<<divup(E, 256), blk, 0, stream>>>(dstp, cntb, E);
  scan_hist<<<1, dim3(1024), 0, stream>>>(cntb, startb, offb, N);
  scatter_edges<<<divup(E, 256), blk, 0, stream>>>(srcp, dstp, eattr, offb,
                                                  se, eid_s, E);

  // layers 0,1: gemm-s writes xb (read-only in fused attn); layer 2: xa
  float*       lay_out[3] = {xb, xb, xa};
  float*       alpha_out[3] = {a1, a2, a3};
  const float* gams[3] = {g1, g2, nullptr};
  const float* bets[3] = {be1, be2, nullptr};

  int stripes = divup(N, 128);
  for (int l = 0; l < 3; l++) {
    int M = cfg[l].M;
    GemmArgs ga;
    float* outs[4] = {(float*)qh, (float*)kh, (float*)vh, lay_out[l]};
    const float* biases[4] = {bq[l], bk[l], bv[l], bs[l]};
    int obfs[4] = {1, 1, 1, 0};
    for (int z = 0; z < 4; z++) {
      ga.Wh[z] = Wh12 + (size_t)(l * 4 + z) * 65536;
      ga.Wl[z] = Wl12 + (size_t)(l * 4 + z) * 65536;
      ga.bias[z] = biases[z];
      ga.out[z] = outs[z];
      ga.obf[z] = obfs[z];
    }
    dim3 gg((M >> 6) * 4 * stripes);
    if (l == 0)      gemm4_lds<192><<<gg, blk, 0, stream>>>(Ah, Al, ga, N, M);
    else             gemm4_lds<256><<<gg, blk, 0, stream>>>(Ah, Al, ga, N, M);

    dim3 gat(divup(N * 64, 256));
    if (l < 2) {
      attn_fused<4, 32, 1><<<gat, blk, 0, stream>>>(
          qh, kh, vh, We[l], startb, se, eid_s, sc, lay_out[l],
          alpha_out[l], N, cfg[l].scale, gams[l], bets[l], Ah, Al,
          nullptr, nullptr, nullptr, nullptr);
    } else {
      attn_fused<6, 24, 0><<<gat, blk, 0, stream>>>(
          qh, kh, vh, We[l], startb, se, eid_s, sc, lay_out[l],
          alpha_out[l], N, cfg[l].scale, nullptr, nullptr, nullptr, nullptr,
          x, batch, pooled, cnt);
    }
  }

  head_mlp<<<B, dim3(64), 0, stream>>>(pooled, cnt, fc1w, fc1b, fc2w, fc2b, logits);
}

// Round 13
// 528.649 us; speedup vs baseline: 1.4002x; 1.4002x over previous
//
#include <hip/hip_runtime.h>
#include <cstdint>
#include <cstddef>

#define DEVINL __device__ __forceinline__

typedef short s16x8 __attribute__((ext_vector_type(8)));   // 8 bf16 in 4 VGPRs
typedef float f32x4 __attribute__((ext_vector_type(4)));
typedef unsigned short u16x4 __attribute__((ext_vector_type(4)));
typedef unsigned short u16x8 __attribute__((ext_vector_type(8)));

DEVINL unsigned short f2bf(float f) {
  unsigned u = __float_as_uint(f);
  unsigned r = (u + 0x7FFFu + ((u >> 16) & 1u)) >> 16;
  return (unsigned short)r;
}
DEVINL float bf2f(unsigned short b) { return __uint_as_float(((unsigned)b) << 16); }

// async global->LDS, 16B per lane; LDS dest = wave-uniform base + lane*16
DEVINL void gl16(const unsigned short* g, unsigned short* l) {
  __builtin_amdgcn_global_load_lds(
      (const __attribute__((address_space(1))) unsigned int*)g,
      (__attribute__((address_space(3))) unsigned int*)l, 16, 0, 0);
}

__global__ __launch_bounds__(256) void fill_i32(int* __restrict__ p, int val, int n) {
  int i = blockIdx.x * 256 + threadIdx.x;
  if (i < n) p[i] = val;
}

// all 12 weight matrices: W[K,M] fp32 -> Wt hi/lo [M,K] bf16
struct CvtWArgs {
  const float* W[12];
  int K[12];
  int M[12];
};

// R23: prologue mega-kernel — cvt_w_all, fill(cntb), fill(pooled) and
// cvt_split are mutually independent; one block-range-dispatched launch
// replaces 4 (whole blocks per branch, no divergence).
// R25 = exact revert of R24's fused atomic pooling (batch is SORTED ->
// ~312 concurrent same-address atomics per pooled cell -> 72->300us;
// hierarchical resid_pool2 restored).
__global__ __launch_bounds__(256) void prologue(
    CvtWArgs a, unsigned short* __restrict__ Wh, unsigned short* __restrict__ Wl,
    const float* __restrict__ xin, unsigned short* __restrict__ Ah,
    unsigned short* __restrict__ Al, int nsplit,
    int* __restrict__ cntb, int ncnt, int* __restrict__ poolz, int npool) {
  int bid = blockIdx.x;
  if (bid < 3072) {
    int tid = bid * 256 + threadIdx.x;
    int mat = tid >> 16;
    int off = tid & 65535;
    if (mat >= 12) return;
    int K = a.K[mat], M = a.M[mat];
    if (off >= K * M) return;
    int k = off / M, m = off - k * M;
    float f = a.W[mat][off];
    unsigned short h = f2bf(f);
    float r = f - bf2f(h);
    size_t dst = (size_t)mat * 65536 + (size_t)m * K + k;
    Wh[dst] = h;
    Wl[dst] = f2bf(r);
  } else if (bid < 3072 + 79) {
    int i = (bid - 3072) * 256 + threadIdx.x;
    if (i < ncnt) cntb[i] = 0;
  } else if (bid < 3200) {
    int i = (bid - 3151) * 256 + threadIdx.x;
    if (i < npool) poolz[i] = 0;
  } else {
    int i = (bid - 3200) * 256 + threadIdx.x;
    if (i >= nsplit) return;
    float f = xin[i];
    unsigned short h = f2bf(f);
    float r = f - bf2f(h);
    Ah[i] = h;
    Al[i] = f2bf(r);
  }
}

// ---------------- LDS-tiled fused 4-matrix MFMA GEMM -------
// R21: staging via __builtin_amdgcn_global_load_lds width=16 (m97/m151
// ladder step).  Linear LDS dest + inverse-XOR-swizzled per-lane GLOBAL
// source + swizzled read (rule #21; XOR is an involution so source-perm ==
// read-perm).  2-barrier loop: issue -> vmcnt(0)+barrier -> compute; no reg
// prefetch (overlap from 3 blocks/CU as in m97).  R14 epilogue, R15 k/v
// de-interleave + XCD swizzle, R20 int2 packing retained.
// obf: 0 = fp32 row, 1 = bf16 row-major (q/k/v).
struct GemmArgs {
  const unsigned short* Wh[4];
  const unsigned short* Wl[4];
  const float* bias[4];
  float* out[4];
  int obf[4];
};

template <int KTOT>   // 192 or 256
__global__ __launch_bounds__(256, 3) void gemm4_lds(
    const unsigned short* __restrict__ Ah, const unsigned short* __restrict__ Al,
    GemmArgs args, int N, int M) {
  const int BK = 64;
  __shared__ unsigned short ash[128 * 64];
  __shared__ unsigned short asl[128 * 64];
  __shared__ unsigned short wsh[64 * 64];
  __shared__ unsigned short wsl[64 * 64];
  int tid = threadIdx.x;
  int wave = tid >> 6, lane = tid & 63;
  int lrow = lane & 15, quad = lane >> 4;
  int mt = M >> 6;
  int ntile = mt * 4;
  // XCD-chunked bijective swizzle: each XCD gets a contiguous run of work
  // ids => complete row-stripes => 16x A-tile reuse happens inside one L2.
  int id = blockIdx.x, nwg = gridDim.x;
  int q8 = nwg >> 3, r8 = nwg & 7;
  int xcd = id & 7, j8 = id >> 3;
  int wg = (xcd < r8 ? xcd * (q8 + 1) : r8 * (q8 + 1) + (xcd - r8) * q8) + j8;
  int by = wg / ntile;
  int bxx = wg - by * ntile;
  int z = bxx / mt;
  int colTile = bxx - z * mt;
  int row0 = by * 128;
  int col0 = colTile * 64;
  const unsigned short* __restrict__ Wh = args.Wh[z];
  const unsigned short* __restrict__ Wl = args.Wl[z];
  const bool full = (args.obf[z] == 0);

  // per-lane source geometry for gload_lds (loop-invariant parts)
  int lr8 = lane >> 3;          // row within 8-row segment
  int kq = lane & 7;            // 16B chunk within row

  f32x4 acc[2][4] = {};

  for (int k0 = 0; k0 < KTOT; k0 += BK) {
    __syncthreads();   // previous step's LDS consumers done
    // A tiles: 16 segments of 1KB each (8 rows x 128B); wave w does s=w+4i
#pragma unroll
    for (int i = 0; i < 4; i++) {
      int s = wave + i * 4;
      int row = s * 8 + lr8;
      int gr = row0 + row; if (gr >= N) gr = N - 1;
      size_t gofs = (size_t)gr * KTOT + k0 + ((kq ^ (row & 7)) * 8);
      gl16(Ah + gofs, ash + s * 512);
      gl16(Al + gofs, asl + s * 512);
    }
    // W tiles: 8 segments
#pragma unroll
    for (int i = 0; i < 2; i++) {
      int s = wave + i * 4;
      int row = s * 8 + lr8;
      size_t gofs = (size_t)(col0 + row) * KTOT + k0 + ((kq ^ (row & 7)) * 8);
      gl16(Wh + gofs, wsh + s * 512);
      if (full) gl16(Wl + gofs, wsl + s * 512);
    }
    asm volatile("s_waitcnt vmcnt(0)" ::: "memory");
    __syncthreads();   // LDS tile visible to all waves
#pragma unroll
    for (int kk = 0; kk < 2; kk++) {
      s16x8 fah[2], fal[2], fbh[4], fbl[4];
#pragma unroll
      for (int rf = 0; rf < 2; rf++) {
        int r = wave * 32 + rf * 16 + lrow;
        int sq = (kk * 4 + quad) ^ (lrow & 7);
        fah[rf] = *(const s16x8*)(ash + r * 64 + sq * 8);
        fal[rf] = *(const s16x8*)(asl + r * 64 + sq * 8);
      }
#pragma unroll
      for (int cf = 0; cf < 4; cf++) {
        int cc = cf * 16 + lrow;
        int sq = (kk * 4 + quad) ^ (lrow & 7);
        fbh[cf] = *(const s16x8*)(wsh + cc * 64 + sq * 8);
        if (full) fbl[cf] = *(const s16x8*)(wsl + cc * 64 + sq * 8);
      }
#pragma unroll
      for (int rf = 0; rf < 2; rf++)
#pragma unroll
        for (int cf = 0; cf < 4; cf++) {
          acc[rf][cf] = __builtin_amdgcn_mfma_f32_16x16x32_bf16(fah[rf], fbh[cf], acc[rf][cf], 0, 0, 0);
          acc[rf][cf] = __builtin_amdgcn_mfma_f32_16x16x32_bf16(fal[rf], fbh[cf], acc[rf][cf], 0, 0, 0);
          if (full)
            acc[rf][cf] = __builtin_amdgcn_mfma_f32_16x16x32_bf16(fah[rf], fbl[cf], acc[rf][cf], 0, 0, 0);
        }
    }
  }
  const float* __restrict__ bias = args.bias[z];
  int obf = args.obf[z];
  if (obf == 0) {
    // fp32 direct stores: each instr covers 4 full 64B lines — already fine
    float* __restrict__ C = args.out[z];
#pragma unroll
    for (int cf = 0; cf < 4; cf++) {
      int col = col0 + cf * 16 + lrow;
      float bv = bias[col];
#pragma unroll
      for (int rf = 0; rf < 2; rf++) {
        int rb = row0 + wave * 32 + rf * 16 + quad * 4;
#pragma unroll
        for (int r = 0; r < 4; r++) {
          int rr = rb + r;
          if (rr < N) C[(size_t)rr * M + col] = acc[rf][cf][r] + bv;
        }
      }
    }
  } else {
    // bf16 row-major: stage u16 tile in ash (free after K-loop), store dense
    __syncthreads();
#pragma unroll
    for (int cf = 0; cf < 4; cf++) {
      int col = cf * 16 + lrow;
      float bv = bias[col0 + col];
#pragma unroll
      for (int rf = 0; rf < 2; rf++) {
        int rl = wave * 32 + rf * 16 + quad * 4;
#pragma unroll
        for (int r = 0; r < 4; r++)
          ash[(rl + r) * 64 + col] = f2bf(acc[rf][cf][r] + bv);
      }
    }
    __syncthreads();
    unsigned short* __restrict__ C = (unsigned short*)args.out[z];
    // row-major M cols, 16B chunks.  1024 chunks / 256 threads.
#pragma unroll
    for (int i = 0; i < 4; i++) {
      int c = tid + i * 256;
      int row = c >> 3, g8 = c & 7;
      int rr = row0 + row;
      if (rr < N)
        *(u16x8*)(C + (size_t)rr * M + col0 + g8 * 8) =
            *(const u16x8*)(ash + row * 64 + g8 * 8);
    }
  }
}

// ---------------- counting sort of edges by dst ----------------

__global__ __launch_bounds__(256) void hist_dst(const int* __restrict__ dst,
                                                int* __restrict__ cnt, int E) {
  int e = blockIdx.x * 256 + threadIdx.x;
  if (e < E) atomicAdd(&cnt[dst[e] + 1], 1);
}

__global__ __launch_bounds__(1024) void scan_hist(const int* __restrict__ cnt,
                                                  int* __restrict__ start,
                                                  int* __restrict__ off, int N) {
  __shared__ int sums[1024];
  const int CH = 20;
  int t = threadIdx.x;
  int base = t * CH;
  int local[CH];
  int tot = 0;
  if (base < N) {
#pragma unroll
    for (int i = 0; i < CH; i++) { local[i] = cnt[base + i]; tot += local[i]; }
  }
  sums[t] = tot;
  __syncthreads();
  for (int d = 1; d < 1024; d <<= 1) {
    int v = (t >= d) ? sums[t - d] : 0;
    __syncthreads();
    sums[t] += v;
    __syncthreads();
  }
  if (base < N) {
    int run = (t == 0) ? 0 : sums[t - 1];
#pragma unroll
    for (int i = 0; i < CH; i++) { start[base + i] = run; off[base + i] = run; run += local[i]; }
    if (base + CH == N) start[N] = run;
  }
}

// R20: {src+1, bits(ea)} packed into one int2 -> 2 stores/edge (one 8B)
// instead of 3 scattered 4B stores; fewer partial-line RMWs on the random
// pos scatter.  eid_s stays separate (read per-lane in alpha writeback).
__global__ __launch_bounds__(256) void scatter_edges(
    const int* __restrict__ src, const int* __restrict__ dst,
    const float* __restrict__ ea, int* __restrict__ off,
    int2* __restrict__ se, int* __restrict__ eid_s, int E) {
  int e = blockIdx.x * 256 + threadIdx.x;
  if (e >= E) return;
  int d = dst[e] + 1;
  int pos = atomicAdd(&off[d], 1);
  se[pos] = make_int2(src[e] + 1, __float_as_int(ea[e]));
  eid_s[pos] = e;
}

// ------- fused per-dst attention.
// R16: 2 edges per wave-step; depth-4 pair pipeline (8 edges in flight);
// cross-half combine via shfl_xor(32).  Attn is at its compulsory-traffic
// floor (157+36)MB / 2.7TB/s — the 8x-XCD k/v replication is invariant for
// dst-parallel order (R22 depth-6 null confirmed).
// R17: MODE 1 fuses LN+ReLU+bf16-split into the epilogue (layers 1,2).
// MODE 0 = layer-3 fp32 "+=" (R24's fused atomic pooling reverted — sorted
// batch makes it a ~312-way same-address atomic serialization, 72->300us).
// R20: packed int2 {src, ea} preload.
template <int H, int ACT, int MODE>
__global__ __launch_bounds__(256) void attn_fused(
    const unsigned short* __restrict__ q, const unsigned short* __restrict__ kb,
    const unsigned short* __restrict__ vb, const float* __restrict__ We,
    const int* __restrict__ start, const int2* __restrict__ se,
    const int* __restrict__ eid_s,
    float* __restrict__ sc, float* __restrict__ outp,
    float* __restrict__ alpha, int Nn, float scale,
    const float* __restrict__ gam, const float* __restrict__ bet,
    unsigned short* __restrict__ hi, unsigned short* __restrict__ lo) {
  const int HC = ACT * 8;
  const int LPH2 = ACT / H;   // lanes per head within a half
  const int D = 4;            // pipeline depth (pairs in flight)
  int w = (blockIdx.x * 256 + threadIdx.x) >> 6;
  int lane = threadIdx.x & 63;
  if (w >= Nn) return;
  int b = start[w], e = start[w + 1];
  int hlane = lane & 31, half = lane >> 5;
  bool act = hlane < ACT;
  int idx = hlane * 8;
  int head = hlane / LPH2;
  float q8[8], We8[8];
#pragma unroll
  for (int j = 0; j < 8; j++) { q8[j] = 0.f; We8[j] = 0.f; }
  if (act) {
    u16x8 qv = *(const u16x8*)(q + (size_t)w * HC + idx);
#pragma unroll
    for (int j = 0; j < 8; j++) q8[j] = bf2f(qv[j]);
    float4 w0 = *(const float4*)(We + idx);
    float4 w1 = *(const float4*)(We + idx + 4);
    We8[0] = w0.x; We8[1] = w0.y; We8[2] = w0.z; We8[3] = w0.w;
    We8[4] = w1.x; We8[5] = w1.y; We8[6] = w1.z; We8[7] = w1.w;
  }
  float qwe = 0.f;
#pragma unroll
  for (int j = 0; j < 8; j++) qwe = fmaf(q8[j], We8[j], qwe);
#pragma unroll
  for (int mm = 1; mm < LPH2; mm <<= 1) qwe += __shfl_xor(qwe, mm, 64);

  float l = 0.f, tv = 0.f;
  float accv[8] = {0.f, 0.f, 0.f, 0.f, 0.f, 0.f, 0.f, 0.f};

  auto step = [&](u16x8 kc, u16x8 vc, float eav, int pairpos) {
    bool vld = (pairpos + half) < e;
    float p = 0.f;
#pragma unroll
    for (int j = 0; j < 8; j++) p = fmaf(q8[j], bf2f(kc[j]), p);
#pragma unroll
    for (int mm = 1; mm < LPH2; mm <<= 1) p += __shfl_xor(p, mm, 64);
    float es = __expf((p + eav * qwe) * scale);
    if (!vld) es = 0.f;
    if (act && vld && (hlane % LPH2) == 0)
      sc[(size_t)(pairpos + half) * H + head] = es;
    l += es;
    tv = fmaf(es, eav, tv);
#pragma unroll
    for (int j = 0; j < 8; j++) accv[j] = fmaf(es, bf2f(vc[j]), accv[j]);
  };

  u16x8 z8 = {0, 0, 0, 0, 0, 0, 0, 0};
  u16x8 kS[D], vS[D];
  float eaS[D];
#pragma unroll
  for (int j = 0; j < D; j++) { kS[j] = z8; vS[j] = z8; eaS[j] = 0.f; }

  auto preload = [&](int pairpos, int st) {
    int pp = pairpos + half;
    int pc = pp < e ? pp : (e - 1);
    int2 pr = se[pc];
    int s = pr.x;
    eaS[st] = __int_as_float(pr.y);
    if (act) {
      kS[st] = *(const u16x8*)(kb + (size_t)s * HC + idx);
      vS[st] = *(const u16x8*)(vb + (size_t)s * HC + idx);
    }
  };

#pragma unroll
  for (int j = 0; j < D; j++) if (b + 2 * j < e) preload(b + 2 * j, j);

  for (int pos = b; pos < e; pos += 2 * D) {
#pragma unroll
    for (int j = 0; j < D; j++) {
      int pp = pos + 2 * j;
      if (pp < e) {
        u16x8 kc = kS[j];
        u16x8 vc = vS[j];
        float ec = eaS[j];
        if (pp + 2 * D < e) preload(pp + 2 * D, j);
        step(kc, vc, ec, pp);
      }
    }
  }

  // combine the two edge-halves
  l += __shfl_xor(l, 32, 64);
  tv += __shfl_xor(tv, 32, 64);
#pragma unroll
  for (int j = 0; j < 8; j++) accv[j] += __shfl_xor(accv[j], 32, 64);

  float invl = 1.0f / (l + 1e-16f);
  if (MODE == 1) {
    // fused LN + relu + bf16 hi/lo split (layers 1,2; ACT==32)
    if (half == 0) {
      const float* orow = outp + (size_t)w * HC + idx;
      float4 o0 = *(const float4*)orow;
      float4 o1 = *(const float4*)(orow + 4);
      float y[8] = {o0.x, o0.y, o0.z, o0.w, o1.x, o1.y, o1.z, o1.w};
#pragma unroll
      for (int j = 0; j < 8; j++) y[j] += (accv[j] + tv * We8[j]) * invl;
      float s = 0.f, s2 = 0.f;
#pragma unroll
      for (int j = 0; j < 8; j++) { s += y[j]; s2 = fmaf(y[j], y[j], s2); }
#pragma unroll
      for (int mm = 1; mm < 32; mm <<= 1) {
        s += __shfl_xor(s, mm, 64);
        s2 += __shfl_xor(s2, mm, 64);
      }
      float mu = s * (1.0f / 256.0f);
      float var = s2 * (1.0f / 256.0f) - mu * mu;
      float rinv = rsqrtf(var + 1e-5f);
      float4 g0 = *(const float4*)(gam + idx);
      float4 g1v = *(const float4*)(gam + idx + 4);
      float4 b0 = *(const float4*)(bet + idx);
      float4 b1 = *(const float4*)(bet + idx + 4);
      float gg[8] = {g0.x, g0.y, g0.z, g0.w, g1v.x, g1v.y, g1v.z, g1v.w};
      float bb[8] = {b0.x, b0.y, b0.z, b0.w, b1.x, b1.y, b1.z, b1.w};
      u16x8 yh, yl;
#pragma unroll
      for (int j = 0; j < 8; j++) {
        float t = fmaxf(fmaf((y[j] - mu) * rinv, gg[j], bb[j]), 0.f);
        unsigned short hh = f2bf(t);
        yh[j] = hh;
        yl[j] = f2bf(t - bf2f(hh));
      }
      *(u16x8*)(hi + (size_t)w * HC + idx) = yh;
      *(u16x8*)(lo + (size_t)w * HC + idx) = yl;
    }
  } else {
    if (act && half == 0) {
      float* orow = outp + (size_t)w * HC + idx;
      float4 o0 = *(float4*)orow;
      float4 o1 = *(float4*)(orow + 4);
      o0.x += (accv[0] + tv * We8[0]) * invl;
      o0.y += (accv[1] + tv * We8[1]) * invl;
      o0.z += (accv[2] + tv * We8[2]) * invl;
      o0.w += (accv[3] + tv * We8[3]) * invl;
      o1.x += (accv[4] + tv * We8[4]) * invl;
      o1.y += (accv[5] + tv * We8[5]) * invl;
      o1.z += (accv[6] + tv * We8[6]) * invl;
      o1.w += (accv[7] + tv * We8[7]) * invl;
      *(float4*)orow = o0;
      *(float4*)(orow + 4) = o1;
    }
  }
  {
    int len = e - b;
    const int PCH = 64 / H;
    int p_of = lane / H;
    int h_of = lane - p_of * H;
    float myinv = __shfl(invl, h_of * LPH2, 64);   // head h_of's denominator
    __threadfence_block();
    for (int base = 0; base < len; base += PCH) {
      int po = base + p_of;
      if (p_of < PCH && po < len) {
        int pos = b + po;
        float es = sc[(size_t)pos * H + h_of];
        alpha[(size_t)eid_s[pos] * H + h_of] = es * myinv;
      }
    }
  }
}

// ---------------- misc dense kernels ----------------

__global__ __launch_bounds__(192) void resid_pool2(
    const float* __restrict__ x, const float* __restrict__ x3,
    const int* __restrict__ batch, float* __restrict__ pooled,
    float* __restrict__ cnt, int N, int R) {
  int col = threadIdx.x;
  int r0 = blockIdx.x * R;
  int r1 = min(r0 + R, N);
  if (r0 >= N) return;
  float acc = 0.f;
  int cur = batch[r0];
  int run = 0;
  for (int r = r0; r < r1; r++) {
    int b = batch[r];
    if (b != cur) {
      atomicAdd(&pooled[cur * 192 + col], acc);
      if (col == 0) atomicAdd(&cnt[cur], (float)run);
      acc = 0.f; run = 0; cur = b;
    }
    size_t i = (size_t)r * 192 + col;
    acc += x[i] + fmaxf(x3[i], 0.f);
    run++;
  }
  atomicAdd(&pooled[cur * 192 + col], acc);
  if (col == 0) atomicAdd(&cnt[cur], (float)run);
}

__global__ __launch_bounds__(64) void head_mlp(
    const float* __restrict__ pooled, const float* __restrict__ cnt,
    const float* __restrict__ fc1w, const float* __restrict__ fc1b,
    const float* __restrict__ fc2w, const float* __restrict__ fc2b,
    float* __restrict__ logits) {
  int b = blockIdx.x;
  int t = threadIdx.x;
  __shared__ float p[192];
  __shared__ float hbuf[32];
  float inv = 1.0f / fmaxf(cnt[b], 1.0f);
  for (int i = t; i < 192; i += 64) p[i] = pooled[b * 192 + i] * inv;
  __syncthreads();
  if (t < 32) {
    float acc = fc1b[t];
    for (int i = 0; i < 192; i++) acc = fmaf(p[i], fc1w[i * 32 + t], acc);
    hbuf[t] = fmaxf(acc, 0.f);
  }
  __syncthreads();
  if (t < 2) {
    float acc = fc2b[t];
    for (int j = 0; j < 32; j++) acc = fmaf(hbuf[j], fc2w[j * 2 + t], acc);
    logits[b * 2 + t] = acc;
  }
}

static inline int divup(int a, int b) { return (a + b - 1) / b; }

extern "C" void kernel_launch(void* const* d_in, const int* in_sizes, int n_in,
                              void* d_out, int out_size, void* d_ws, size_t ws_size,
                              hipStream_t stream) {
  const int N = 20000, E = 320000, B = 64;
  const float* x     = (const float*)d_in[0];
  const int*   ei    = (const int*)d_in[1];
  const float* eattr = (const float*)d_in[2];
  const int*   batch = (const int*)d_in[3];
  const int* srcp = ei;
  const int* dstp = ei + E;

  const float* Wq[3]; const float* bq[3]; const float* Wk[3]; const float* bk[3];
  const float* Wv[3]; const float* bv[3]; const float* We[3]; const float* Ws[3];
  const float* bs[3];
  for (int l = 0; l < 3; l++) {
    int base = 4 + l * 9;
    Wq[l] = (const float*)d_in[base + 0]; bq[l] = (const float*)d_in[base + 1];
    Wk[l] = (const float*)d_in[base + 2]; bk[l] = (const float*)d_in[base + 3];
    Wv[l] = (const float*)d_in[base + 4]; bv[l] = (const float*)d_in[base + 5];
    We[l] = (const float*)d_in[base + 6];
    Ws[l] = (const float*)d_in[base + 7]; bs[l] = (const float*)d_in[base + 8];
  }
  const float* g1  = (const float*)d_in[31]; const float* be1 = (const float*)d_in[32];
  const float* g2  = (const float*)d_in[33]; const float* be2 = (const float*)d_in[34];
  const float* fc1w = (const float*)d_in[35]; const float* fc1b = (const float*)d_in[36];
  const float* fc2w = (const float*)d_in[37]; const float* fc2b = (const float*)d_in[38];

  float* out = (float*)d_out;
  float* logits = out;
  float* a1 = out + 128;
  float* a2 = a1 + (size_t)E * 4;
  float* a3 = a2 + (size_t)E * 4;

  float* ws = (float*)d_ws;
  size_t o = 0;
  float* qb = ws + o; o += (size_t)N * 256;   // bf16 q (oversized ok)
  float* kvb = ws + o; o += (size_t)N * 256;  // bf16 k then v (N*256 u16 each)
  float* xa = ws + o; o += (size_t)N * 256;
  float* xb = ws + o; o += (size_t)N * 256;
  float* sc = ws + o; o += (size_t)E * 6;
  int*   cntb  = (int*)(ws + o); o += N;
  int*   startb= (int*)(ws + o); o += N + 1;
  int*   offb  = (int*)(ws + o); o += N + 1;
  int2*  se    = (int2*)(ws + o); o += (size_t)E * 2;   // 8B-aligned (o even)
  int*   eid_s = (int*)(ws + o); o += E;
  float* pooled = ws + o; o += (size_t)B * 192;
  float* cnt    = ws + o; o += B;
  unsigned short* Ah = (unsigned short*)(ws + o); o += (size_t)N * 128;
  unsigned short* Al = (unsigned short*)(ws + o); o += (size_t)N * 128;
  unsigned short* Wh12 = (unsigned short*)(ws + o); o += (size_t)12 * 32768;
  unsigned short* Wl12 = (unsigned short*)(ws + o); o += (size_t)12 * 32768;

  unsigned short* qh = (unsigned short*)qb;
  unsigned short* kh = (unsigned short*)kvb;
  unsigned short* vh = kh + (size_t)N * 256;

  dim3 blk(256);

  struct LayerCfg { int K, M; float scale; };
  LayerCfg cfg[3] = {
    {192, 256, 0.125f},
    {256, 256, 0.125f},
    {256, 192, 0.1767766952966369f},
  };
  CvtWArgs cwa;
  for (int l = 0; l < 3; l++) {
    cwa.W[l * 4 + 0] = Wq[l]; cwa.W[l * 4 + 1] = Wk[l];
    cwa.W[l * 4 + 2] = Wv[l]; cwa.W[l * 4 + 3] = Ws[l];
    for (int zz = 0; zz < 4; zz++) {
      cwa.K[l * 4 + zz] = cfg[l].K; cwa.M[l * 4 + zz] = cfg[l].M;
    }
  }

  // prologue: cvt_w_all + fill(cntb) + fill(pooled+cnt) + cvt_split fused
  prologue<<<3200 + divup(N * 192, 256), blk, 0, stream>>>(
      cwa, Wh12, Wl12, x, Ah, Al, N * 192, cntb, N, (int*)pooled, B * 192 + B);

  hist_dst<<<divup(E, 256), blk, 0, stream>>>(dstp, cntb, E);
  scan_hist<<<1, dim3(1024), 0, stream>>>(cntb, startb, offb, N);
  scatter_edges<<<divup(E, 256), blk, 0, stream>>>(srcp, dstp, eattr, offb,
                                                  se, eid_s, E);

  // layers 0,1: gemm-s writes xb (read-only in fused attn); layer 2: xa (+=)
  float*       lay_out[3] = {xb, xb, xa};
  float*       alpha_out[3] = {a1, a2, a3};
  const float* gams[3] = {g1, g2, nullptr};
  const float* bets[3] = {be1, be2, nullptr};

  int stripes = divup(N, 128);
  for (int l = 0; l < 3; l++) {
    int M = cfg[l].M;
    GemmArgs ga;
    float* outs[4] = {(float*)qh, (float*)kh, (float*)vh, lay_out[l]};
    const float* biases[4] = {bq[l], bk[l], bv[l], bs[l]};
    int obfs[4] = {1, 1, 1, 0};
    for (int z = 0; z < 4; z++) {
      ga.Wh[z] = Wh12 + (size_t)(l * 4 + z) * 65536;
      ga.Wl[z] = Wl12 + (size_t)(l * 4 + z) * 65536;
      ga.bias[z] = biases[z];
      ga.out[z] = outs[z];
      ga.obf[z] = obfs[z];
    }
    dim3 gg((M >> 6) * 4 * stripes);
    if (l == 0)      gemm4_lds<192><<<gg, blk, 0, stream>>>(Ah, Al, ga, N, M);
    else             gemm4_lds<256><<<gg, blk, 0, stream>>>(Ah, Al, ga, N, M);

    dim3 gat(divup(N * 64, 256));
    if (l < 2) {
      attn_fused<4, 32, 1><<<gat, blk, 0, stream>>>(
          qh, kh, vh, We[l], startb, se, eid_s, sc, lay_out[l],
          alpha_out[l], N, cfg[l].scale, gams[l], bets[l], Ah, Al);
    } else {
      attn_fused<6, 24, 0><<<gat, blk, 0, stream>>>(
          qh, kh, vh, We[l], startb, se, eid_s, sc, lay_out[l],
          alpha_out[l], N, cfg[l].scale, nullptr, nullptr, nullptr, nullptr);
    }
  }

  resid_pool2<<<divup(N, 32), dim3(192), 0, stream>>>(x, xa, batch, pooled, cnt, N, 32);
  head_mlp<<<B, dim3(64), 0, stream>>>(pooled, cnt, fc1w, fc1b, fc2w, fc2b, logits);
}

// Round 14
// 511.099 us; speedup vs baseline: 1.4482x; 1.0343x over previous
//
#include <hip/hip_runtime.h>
#include <cstdint>
#include <cstddef>

#define DEVINL __device__ __forceinline__

typedef short s16x8 __attribute__((ext_vector_type(8)));   // 8 bf16 in 4 VGPRs
typedef float f32x4 __attribute__((ext_vector_type(4)));
typedef unsigned short u16x4 __attribute__((ext_vector_type(4)));
typedef unsigned short u16x8 __attribute__((ext_vector_type(8)));

DEVINL unsigned short f2bf(float f) {
  unsigned u = __float_as_uint(f);
  unsigned r = (u + 0x7FFFu + ((u >> 16) & 1u)) >> 16;
  return (unsigned short)r;
}
DEVINL float bf2f(unsigned short b) { return __uint_as_float(((unsigned)b) << 16); }

// async global->LDS, 16B per lane; LDS dest = wave-uniform base + lane*16
DEVINL void gl16(const unsigned short* g, unsigned short* l) {
  __builtin_amdgcn_global_load_lds(
      (const __attribute__((address_space(1))) unsigned int*)g,
      (__attribute__((address_space(3))) unsigned int*)l, 16, 0, 0);
}

__global__ __launch_bounds__(256) void fill_i32(int* __restrict__ p, int val, int n) {
  int i = blockIdx.x * 256 + threadIdx.x;
  if (i < n) p[i] = val;
}

// all 12 weight matrices: W[K,M] fp32 -> Wt hi/lo [M,K] bf16
struct CvtWArgs {
  const float* W[12];
  int K[12];
  int M[12];
};

// R23: prologue mega-kernel — cvt_w_all, fill(cntb), fill(pooled) and
// cvt_split fused into one block-range-dispatched launch.
__global__ __launch_bounds__(256) void prologue(
    CvtWArgs a, unsigned short* __restrict__ Wh, unsigned short* __restrict__ Wl,
    const float* __restrict__ xin, unsigned short* __restrict__ Ah,
    unsigned short* __restrict__ Al, int nsplit,
    int* __restrict__ cntb, int ncnt, int* __restrict__ poolz, int npool) {
  int bid = blockIdx.x;
  if (bid < 3072) {
    int tid = bid * 256 + threadIdx.x;
    int mat = tid >> 16;
    int off = tid & 65535;
    if (mat >= 12) return;
    int K = a.K[mat], M = a.M[mat];
    if (off >= K * M) return;
    int k = off / M, m = off - k * M;
    float f = a.W[mat][off];
    unsigned short h = f2bf(f);
    float r = f - bf2f(h);
    size_t dst = (size_t)mat * 65536 + (size_t)m * K + k;
    Wh[dst] = h;
    Wl[dst] = f2bf(r);
  } else if (bid < 3072 + 79) {
    int i = (bid - 3072) * 256 + threadIdx.x;
    if (i < ncnt) cntb[i] = 0;
  } else if (bid < 3200) {
    int i = (bid - 3151) * 256 + threadIdx.x;
    if (i < npool) poolz[i] = 0;
  } else {
    int i = (bid - 3200) * 256 + threadIdx.x;
    if (i >= nsplit) return;
    float f = xin[i];
    unsigned short h = f2bf(f);
    float r = f - bf2f(h);
    Ah[i] = h;
    Al[i] = f2bf(r);
  }
}

// ---------------- z-pair-fused LDS-tiled MFMA GEMM -------
// R26: gemm FETCH was 85MB vs A(hi+lo)=20.5MB — 4x replication, one A-read
// per z-matrix (the stripe's A is NOT staying L2-resident across z-blocks).
// One block now computes TWO matrices (zp=0 -> {q,k}, zp=1 -> {v,s}) on a
// 64-row x 64-col tile: A staged once per pair -> A fetch halves
// structurally, independent of cache/XCD-mapping behavior.
// Geometry: 4 waves x 16 rows (rf=1); acc = 2z x 4cf x f32x4 = 32 VGPR;
// LDS = ash+asl+wsa+wsb+wlb = 40KB -> 4 blocks/CU.
// R21 retained: gload_lds width-16, linear LDS dest + inverse-XOR-swizzled
// global source + swizzled read (rule #21); 2-barrier loop.
// obf: 0 = fp32 row, 1 = bf16 row-major.  z_a (q,v) is always bf16;
// z_b is k (bf16) for zp=0, s (fp32, needs W-lo) for zp=1.
struct GemmArgs {
  const unsigned short* Wh[4];
  const unsigned short* Wl[4];
  const float* bias[4];
  float* out[4];
  int obf[4];
};

template <int KTOT>   // 192 or 256
__global__ __launch_bounds__(256, 4) void gemm2z_lds(
    const unsigned short* __restrict__ Ah, const unsigned short* __restrict__ Al,
    GemmArgs args, int N, int M) {
  const int BK = 64;
  __shared__ unsigned short ash[64 * 64];
  __shared__ unsigned short asl[64 * 64];
  __shared__ unsigned short wsa[64 * 64];
  __shared__ unsigned short wsb[64 * 64];
  __shared__ unsigned short wlb[64 * 64];
  int tid = threadIdx.x;
  int wave = tid >> 6, lane = tid & 63;
  int lrow = lane & 15, quad = lane >> 4;
  int mt = M >> 6;
  int ntile = mt * 2;
  // XCD-chunked bijective swizzle (same-stripe blocks stay contiguous)
  int id = blockIdx.x, nwg = gridDim.x;
  int q8 = nwg >> 3, r8 = nwg & 7;
  int xcd = id & 7, j8 = id >> 3;
  int wg = (xcd < r8 ? xcd * (q8 + 1) : r8 * (q8 + 1) + (xcd - r8) * q8) + j8;
  int by = wg / ntile;
  int rem = wg - by * ntile;
  int zp = rem / mt;
  int colTile = rem - zp * mt;
  int row0 = by * 64;
  int col0 = colTile * 64;
  int za = zp * 2, zb = za + 1;
  const unsigned short* __restrict__ Wha = args.Wh[za];
  const unsigned short* __restrict__ Whb = args.Wh[zb];
  const unsigned short* __restrict__ Wlb = args.Wl[zb];
  const bool fullb = (args.obf[zb] == 0);

  int lr8 = lane >> 3;          // row within 8-row segment
  int kq = lane & 7;            // 16B chunk within row

  f32x4 accA[4] = {};
  f32x4 accB[4] = {};

  for (int k0 = 0; k0 < KTOT; k0 += BK) {
    __syncthreads();   // previous step's LDS consumers done
    // A tile: 8 segments of 1KB (8 rows x 128B); wave does s = wave, wave+4
#pragma unroll
    for (int i = 0; i < 2; i++) {
      int s = wave + i * 4;
      int row = s * 8 + lr8;
      int gr = row0 + row; if (gr >= N) gr = N - 1;
      size_t gofs = (size_t)gr * KTOT + k0 + ((kq ^ (row & 7)) * 8);
      gl16(Ah + gofs, ash + s * 512);
      gl16(Al + gofs, asl + s * 512);
    }
    // W tiles: 8 segments each
#pragma unroll
    for (int i = 0; i < 2; i++) {
      int s = wave + i * 4;
      int c = s * 8 + lr8;
      size_t gofs = (size_t)(col0 + c) * KTOT + k0 + ((kq ^ (c & 7)) * 8);
      gl16(Wha + gofs, wsa + s * 512);
      gl16(Whb + gofs, wsb + s * 512);
      if (fullb) gl16(Wlb + gofs, wlb + s * 512);
    }
    asm volatile("s_waitcnt vmcnt(0)" ::: "memory");
    __syncthreads();   // LDS tile visible to all waves
#pragma unroll
    for (int kk = 0; kk < 2; kk++) {
      int sq = (kk * 4 + quad) ^ (lrow & 7);
      int r = wave * 16 + lrow;
      s16x8 fah = *(const s16x8*)(ash + r * 64 + sq * 8);
      s16x8 fal = *(const s16x8*)(asl + r * 64 + sq * 8);
      s16x8 fba[4], fbb[4], fbl[4];
#pragma unroll
      for (int cf = 0; cf < 4; cf++) {
        int cc = cf * 16 + lrow;
        fba[cf] = *(const s16x8*)(wsa + cc * 64 + sq * 8);
        fbb[cf] = *(const s16x8*)(wsb + cc * 64 + sq * 8);
        if (fullb) fbl[cf] = *(const s16x8*)(wlb + cc * 64 + sq * 8);
      }
#pragma unroll
      for (int cf = 0; cf < 4; cf++) {
        accA[cf] = __builtin_amdgcn_mfma_f32_16x16x32_bf16(fah, fba[cf], accA[cf], 0, 0, 0);
        accA[cf] = __builtin_amdgcn_mfma_f32_16x16x32_bf16(fal, fba[cf], accA[cf], 0, 0, 0);
        accB[cf] = __builtin_amdgcn_mfma_f32_16x16x32_bf16(fah, fbb[cf], accB[cf], 0, 0, 0);
        accB[cf] = __builtin_amdgcn_mfma_f32_16x16x32_bf16(fal, fbb[cf], accB[cf], 0, 0, 0);
        if (fullb)
          accB[cf] = __builtin_amdgcn_mfma_f32_16x16x32_bf16(fah, fbl[cf], accB[cf], 0, 0, 0);
      }
    }
  }
  const float* __restrict__ biasA = args.bias[za];
  const float* __restrict__ biasB = args.bias[zb];
  __syncthreads();   // LDS free for epilogue staging
  // stage za (always bf16) into ash; zb into asl if bf16
#pragma unroll
  for (int cf = 0; cf < 4; cf++) {
    int col = cf * 16 + lrow;
    float bva = biasA[col0 + col];
    int rl = wave * 16 + quad * 4;
#pragma unroll
    for (int r = 0; r < 4; r++)
      ash[(rl + r) * 64 + col] = f2bf(accA[cf][r] + bva);
  }
  if (!fullb) {
#pragma unroll
    for (int cf = 0; cf < 4; cf++) {
      int col = cf * 16 + lrow;
      float bvb = biasB[col0 + col];
      int rl = wave * 16 + quad * 4;
#pragma unroll
      for (int r = 0; r < 4; r++)
        asl[(rl + r) * 64 + col] = f2bf(accB[cf][r] + bvb);
    }
  }
  __syncthreads();
  {
    unsigned short* __restrict__ Ca = (unsigned short*)args.out[za];
    // 64 rows x 8 chunks = 512 chunks / 256 threads
#pragma unroll
    for (int i = 0; i < 2; i++) {
      int c = tid + i * 256;
      int row = c >> 3, g8 = c & 7;
      int rr = row0 + row;
      if (rr < N)
        *(u16x8*)(Ca + (size_t)rr * M + col0 + g8 * 8) =
            *(const u16x8*)(ash + row * 64 + g8 * 8);
    }
  }
  if (!fullb) {
    unsigned short* __restrict__ Cb = (unsigned short*)args.out[zb];
#pragma unroll
    for (int i = 0; i < 2; i++) {
      int c = tid + i * 256;
      int row = c >> 3, g8 = c & 7;
      int rr = row0 + row;
      if (rr < N)
        *(u16x8*)(Cb + (size_t)rr * M + col0 + g8 * 8) =
            *(const u16x8*)(asl + row * 64 + g8 * 8);
    }
  } else {
    // fp32 direct stores (s-matrix)
    float* __restrict__ Cb = args.out[zb];
#pragma unroll
    for (int cf = 0; cf < 4; cf++) {
      int col = col0 + cf * 16 + lrow;
      float bv = biasB[col];
      int rb = row0 + wave * 16 + quad * 4;
#pragma unroll
      for (int r = 0; r < 4; r++) {
        int rr = rb + r;
        if (rr < N) Cb[(size_t)rr * M + col] = accB[cf][r] + bv;
      }
    }
  }
}

// ---------------- counting sort of edges by dst ----------------

__global__ __launch_bounds__(256) void hist_dst(const int* __restrict__ dst,
                                                int* __restrict__ cnt, int E) {
  int e = blockIdx.x * 256 + threadIdx.x;
  if (e < E) atomicAdd(&cnt[dst[e] + 1], 1);
}

__global__ __launch_bounds__(1024) void scan_hist(const int* __restrict__ cnt,
                                                  int* __restrict__ start,
                                                  int* __restrict__ off, int N) {
  __shared__ int sums[1024];
  const int CH = 20;
  int t = threadIdx.x;
  int base = t * CH;
  int local[CH];
  int tot = 0;
  if (base < N) {
#pragma unroll
    for (int i = 0; i < CH; i++) { local[i] = cnt[base + i]; tot += local[i]; }
  }
  sums[t] = tot;
  __syncthreads();
  for (int d = 1; d < 1024; d <<= 1) {
    int v = (t >= d) ? sums[t - d] : 0;
    __syncthreads();
    sums[t] += v;
    __syncthreads();
  }
  if (base < N) {
    int run = (t == 0) ? 0 : sums[t - 1];
#pragma unroll
    for (int i = 0; i < CH; i++) { start[base + i] = run; off[base + i] = run; run += local[i]; }
    if (base + CH == N) start[N] = run;
  }
}

// R20: {src+1, bits(ea)} packed into one int2 -> 2 stores/edge (one 8B).
__global__ __launch_bounds__(256) void scatter_edges(
    const int* __restrict__ src, const int* __restrict__ dst,
    const float* __restrict__ ea, int* __restrict__ off,
    int2* __restrict__ se, int* __restrict__ eid_s, int E) {
  int e = blockIdx.x * 256 + threadIdx.x;
  if (e >= E) return;
  int d = dst[e] + 1;
  int pos = atomicAdd(&off[d], 1);
  se[pos] = make_int2(src[e] + 1, __float_as_int(ea[e]));
  eid_s[pos] = e;
}

// ------- fused per-dst attention.
// R16: 2 edges per wave-step; depth-4 pair pipeline (8 edges in flight);
// cross-half combine via shfl_xor(32).  Attn is at its compulsory-traffic
// floor (157+36)MB / 2.7TB/s — the 8x-XCD k/v replication is invariant for
// dst-parallel order (R22 depth-6 null confirmed).
// R17: MODE 1 fuses LN+ReLU+bf16-split into the epilogue (layers 1,2).
// MODE 0 = layer-3 fp32 "+=" (R24's fused atomic pooling reverted — sorted
// batch makes it a ~312-way same-address atomic serialization, 72->300us).
// R20: packed int2 {src, ea} preload.
template <int H, int ACT, int MODE>
__global__ __launch_bounds__(256) void attn_fused(
    const unsigned short* __restrict__ q, const unsigned short* __restrict__ kb,
    const unsigned short* __restrict__ vb, const float* __restrict__ We,
    const int* __restrict__ start, const int2* __restrict__ se,
    const int* __restrict__ eid_s,
    float* __restrict__ sc, float* __restrict__ outp,
    float* __restrict__ alpha, int Nn, float scale,
    const float* __restrict__ gam, const float* __restrict__ bet,
    unsigned short* __restrict__ hi, unsigned short* __restrict__ lo) {
  const int HC = ACT * 8;
  const int LPH2 = ACT / H;   // lanes per head within a half
  const int D = 4;            // pipeline depth (pairs in flight)
  int w = (blockIdx.x * 256 + threadIdx.x) >> 6;
  int lane = threadIdx.x & 63;
  if (w >= Nn) return;
  int b = start[w], e = start[w + 1];
  int hlane = lane & 31, half = lane >> 5;
  bool act = hlane < ACT;
  int idx = hlane * 8;
  int head = hlane / LPH2;
  float q8[8], We8[8];
#pragma unroll
  for (int j = 0; j < 8; j++) { q8[j] = 0.f; We8[j] = 0.f; }
  if (act) {
    u16x8 qv = *(const u16x8*)(q + (size_t)w * HC + idx);
#pragma unroll
    for (int j = 0; j < 8; j++) q8[j] = bf2f(qv[j]);
    float4 w0 = *(const float4*)(We + idx);
    float4 w1 = *(const float4*)(We + idx + 4);
    We8[0] = w0.x; We8[1] = w0.y; We8[2] = w0.z; We8[3] = w0.w;
    We8[4] = w1.x; We8[5] = w1.y; We8[6] = w1.z; We8[7] = w1.w;
  }
  float qwe = 0.f;
#pragma unroll
  for (int j = 0; j < 8; j++) qwe = fmaf(q8[j], We8[j], qwe);
#pragma unroll
  for (int mm = 1; mm < LPH2; mm <<= 1) qwe += __shfl_xor(qwe, mm, 64);

  float l = 0.f, tv = 0.f;
  float accv[8] = {0.f, 0.f, 0.f, 0.f, 0.f, 0.f, 0.f, 0.f};

  auto step = [&](u16x8 kc, u16x8 vc, float eav, int pairpos) {
    bool vld = (pairpos + half) < e;
    float p = 0.f;
#pragma unroll
    for (int j = 0; j < 8; j++) p = fmaf(q8[j], bf2f(kc[j]), p);
#pragma unroll
    for (int mm = 1; mm < LPH2; mm <<= 1) p += __shfl_xor(p, mm, 64);
    float es = __expf((p + eav * qwe) * scale);
    if (!vld) es = 0.f;
    if (act && vld && (hlane % LPH2) == 0)
      sc[(size_t)(pairpos + half) * H + head] = es;
    l += es;
    tv = fmaf(es, eav, tv);
#pragma unroll
    for (int j = 0; j < 8; j++) accv[j] = fmaf(es, bf2f(vc[j]), accv[j]);
  };

  u16x8 z8 = {0, 0, 0, 0, 0, 0, 0, 0};
  u16x8 kS[D], vS[D];
  float eaS[D];
#pragma unroll
  for (int j = 0; j < D; j++) { kS[j] = z8; vS[j] = z8; eaS[j] = 0.f; }

  auto preload = [&](int pairpos, int st) {
    int pp = pairpos + half;
    int pc = pp < e ? pp : (e - 1);
    int2 pr = se[pc];
    int s = pr.x;
    eaS[st] = __int_as_float(pr.y);
    if (act) {
      kS[st] = *(const u16x8*)(kb + (size_t)s * HC + idx);
      vS[st] = *(const u16x8*)(vb + (size_t)s * HC + idx);
    }
  };

#pragma unroll
  for (int j = 0; j < D; j++) if (b + 2 * j < e) preload(b + 2 * j, j);

  for (int pos = b; pos < e; pos += 2 * D) {
#pragma unroll
    for (int j = 0; j < D; j++) {
      int pp = pos + 2 * j;
      if (pp < e) {
        u16x8 kc = kS[j];
        u16x8 vc = vS[j];
        float ec = eaS[j];
        if (pp + 2 * D < e) preload(pp + 2 * D, j);
        step(kc, vc, ec, pp);
      }
    }
  }

  // combine the two edge-halves
  l += __shfl_xor(l, 32, 64);
  tv += __shfl_xor(tv, 32, 64);
#pragma unroll
  for (int j = 0; j < 8; j++) accv[j] += __shfl_xor(accv[j], 32, 64);

  float invl = 1.0f / (l + 1e-16f);
  if (MODE == 1) {
    // fused LN + relu + bf16 hi/lo split (layers 1,2; ACT==32)
    if (half == 0) {
      const float* orow = outp + (size_t)w * HC + idx;
      float4 o0 = *(const float4*)orow;
      float4 o1 = *(const float4*)(orow + 4);
      float y[8] = {o0.x, o0.y, o0.z, o0.w, o1.x, o1.y, o1.z, o1.w};
#pragma unroll
      for (int j = 0; j < 8; j++) y[j] += (accv[j] + tv * We8[j]) * invl;
      float s = 0.f, s2 = 0.f;
#pragma unroll
      for (int j = 0; j < 8; j++) { s += y[j]; s2 = fmaf(y[j], y[j], s2); }
#pragma unroll
      for (int mm = 1; mm < 32; mm <<= 1) {
        s += __shfl_xor(s, mm, 64);
        s2 += __shfl_xor(s2, mm, 64);
      }
      float mu = s * (1.0f / 256.0f);
      float var = s2 * (1.0f / 256.0f) - mu * mu;
      float rinv = rsqrtf(var + 1e-5f);
      float4 g0 = *(const float4*)(gam + idx);
      float4 g1v = *(const float4*)(gam + idx + 4);
      float4 b0 = *(const float4*)(bet + idx);
      float4 b1 = *(const float4*)(bet + idx + 4);
      float gg[8] = {g0.x, g0.y, g0.z, g0.w, g1v.x, g1v.y, g1v.z, g1v.w};
      float bb[8] = {b0.x, b0.y, b0.z, b0.w, b1.x, b1.y, b1.z, b1.w};
      u16x8 yh, yl;
#pragma unroll
      for (int j = 0; j < 8; j++) {
        float t = fmaxf(fmaf((y[j] - mu) * rinv, gg[j], bb[j]), 0.f);
        unsigned short hh = f2bf(t);
        yh[j] = hh;
        yl[j] = f2bf(t - bf2f(hh));
      }
      *(u16x8*)(hi + (size_t)w * HC + idx) = yh;
      *(u16x8*)(lo + (size_t)w * HC + idx) = yl;
    }
  } else {
    if (act && half == 0) {
      float* orow = outp + (size_t)w * HC + idx;
      float4 o0 = *(float4*)orow;
      float4 o1 = *(float4*)(orow + 4);
      o0.x += (accv[0] + tv * We8[0]) * invl;
      o0.y += (accv[1] + tv * We8[1]) * invl;
      o0.z += (accv[2] + tv * We8[2]) * invl;
      o0.w += (accv[3] + tv * We8[3]) * invl;
      o1.x += (accv[4] + tv * We8[4]) * invl;
      o1.y += (accv[5] + tv * We8[5]) * invl;
      o1.z += (accv[6] + tv * We8[6]) * invl;
      o1.w += (accv[7] + tv * We8[7]) * invl;
      *(float4*)orow = o0;
      *(float4*)(orow + 4) = o1;
    }
  }
  {
    int len = e - b;
    const int PCH = 64 / H;
    int p_of = lane / H;
    int h_of = lane - p_of * H;
    float myinv = __shfl(invl, h_of * LPH2, 64);   // head h_of's denominator
    __threadfence_block();
    for (int base = 0; base < len; base += PCH) {
      int po = base + p_of;
      if (p_of < PCH && po < len) {
        int pos = b + po;
        float es = sc[(size_t)pos * H + h_of];
        alpha[(size_t)eid_s[pos] * H + h_of] = es * myinv;
      }
    }
  }
}

// ---------------- misc dense kernels ----------------

__global__ __launch_bounds__(192) void resid_pool2(
    const float* __restrict__ x, const float* __restrict__ x3,
    const int* __restrict__ batch, float* __restrict__ pooled,
    float* __restrict__ cnt, int N, int R) {
  int col = threadIdx.x;
  int r0 = blockIdx.x * R;
  int r1 = min(r0 + R, N);
  if (r0 >= N) return;
  float acc = 0.f;
  int cur = batch[r0];
  int run = 0;
  for (int r = r0; r < r1; r++) {
    int b = batch[r];
    if (b != cur) {
      atomicAdd(&pooled[cur * 192 + col], acc);
      if (col == 0) atomicAdd(&cnt[cur], (float)run);
      acc = 0.f; run = 0; cur = b;
    }
    size_t i = (size_t)r * 192 + col;
    acc += x[i] + fmaxf(x3[i], 0.f);
    run++;
  }
  atomicAdd(&pooled[cur * 192 + col], acc);
  if (col == 0) atomicAdd(&cnt[cur], (float)run);
}

__global__ __launch_bounds__(64) void head_mlp(
    const float* __restrict__ pooled, const float* __restrict__ cnt,
    const float* __restrict__ fc1w, const float* __restrict__ fc1b,
    const float* __restrict__ fc2w, const float* __restrict__ fc2b,
    float* __restrict__ logits) {
  int b = blockIdx.x;
  int t = threadIdx.x;
  __shared__ float p[192];
  __shared__ float hbuf[32];
  float inv = 1.0f / fmaxf(cnt[b], 1.0f);
  for (int i = t; i < 192; i += 64) p[i] = pooled[b * 192 + i] * inv;
  __syncthreads();
  if (t < 32) {
    float acc = fc1b[t];
    for (int i = 0; i < 192; i++) acc = fmaf(p[i], fc1w[i * 32 + t], acc);
    hbuf[t] = fmaxf(acc, 0.f);
  }
  __syncthreads();
  if (t < 2) {
    float acc = fc2b[t];
    for (int j = 0; j < 32; j++) acc = fmaf(hbuf[j], fc2w[j * 2 + t], acc);
    logits[b * 2 + t] = acc;
  }
}

static inline int divup(int a, int b) { return (a + b - 1) / b; }

extern "C" void kernel_launch(void* const* d_in, const int* in_sizes, int n_in,
                              void* d_out, int out_size, void* d_ws, size_t ws_size,
                              hipStream_t stream) {
  const int N = 20000, E = 320000, B = 64;
  const float* x     = (const float*)d_in[0];
  const int*   ei    = (const int*)d_in[1];
  const float* eattr = (const float*)d_in[2];
  const int*   batch = (const int*)d_in[3];
  const int* srcp = ei;
  const int* dstp = ei + E;

  const float* Wq[3]; const float* bq[3]; const float* Wk[3]; const float* bk[3];
  const float* Wv[3]; const float* bv[3]; const float* We[3]; const float* Ws[3];
  const float* bs[3];
  for (int l = 0; l < 3; l++) {
    int base = 4 + l * 9;
    Wq[l] = (const float*)d_in[base + 0]; bq[l] = (const float*)d_in[base + 1];
    Wk[l] = (const float*)d_in[base + 2]; bk[l] = (const float*)d_in[base + 3];
    Wv[l] = (const float*)d_in[base + 4]; bv[l] = (const float*)d_in[base + 5];
    We[l] = (const float*)d_in[base + 6];
    Ws[l] = (const float*)d_in[base + 7]; bs[l] = (const float*)d_in[base + 8];
  }
  const float* g1  = (const float*)d_in[31]; const float* be1 = (const float*)d_in[32];
  const float* g2  = (const float*)d_in[33]; const float* be2 = (const float*)d_in[34];
  const float* fc1w = (const float*)d_in[35]; const float* fc1b = (const float*)d_in[36];
  const float* fc2w = (const float*)d_in[37]; const float* fc2b = (const float*)d_in[38];

  float* out = (float*)d_out;
  float* logits = out;
  float* a1 = out + 128;
  float* a2 = a1 + (size_t)E * 4;
  float* a3 = a2 + (size_t)E * 4;

  float* ws = (float*)d_ws;
  size_t o = 0;
  float* qb = ws + o; o += (size_t)N * 256;   // bf16 q (oversized ok)
  float* kvb = ws + o; o += (size_t)N * 256;  // bf16 k then v (N*256 u16 each)
  float* xa = ws + o; o += (size_t)N * 256;
  float* xb = ws + o; o += (size_t)N * 256;
  float* sc = ws + o; o += (size_t)E * 6;
  int*   cntb  = (int*)(ws + o); o += N;
  int*   startb= (int*)(ws + o); o += N + 1;
  int*   offb  = (int*)(ws + o); o += N + 1;
  int2*  se    = (int2*)(ws + o); o += (size_t)E * 2;   // 8B-aligned (o even)
  int*   eid_s = (int*)(ws + o); o += E;
  float* pooled = ws + o; o += (size_t)B * 192;
  float* cnt    = ws + o; o += B;
  unsigned short* Ah = (unsigned short*)(ws + o); o += (size_t)N * 128;
  unsigned short* Al = (unsigned short*)(ws + o); o += (size_t)N * 128;
  unsigned short* Wh12 = (unsigned short*)(ws + o); o += (size_t)12 * 32768;
  unsigned short* Wl12 = (unsigned short*)(ws + o); o += (size_t)12 * 32768;

  unsigned short* qh = (unsigned short*)qb;
  unsigned short* kh = (unsigned short*)kvb;
  unsigned short* vh = kh + (size_t)N * 256;

  dim3 blk(256);

  struct LayerCfg { int K, M; float scale; };
  LayerCfg cfg[3] = {
    {192, 256, 0.125f},
    {256, 256, 0.125f},
    {256, 192, 0.1767766952966369f},
  };
  CvtWArgs cwa;
  for (int l = 0; l < 3; l++) {
    cwa.W[l * 4 + 0] = Wq[l]; cwa.W[l * 4 + 1] = Wk[l];
    cwa.W[l * 4 + 2] = Wv[l]; cwa.W[l * 4 + 3] = Ws[l];
    for (int zz = 0; zz < 4; zz++) {
      cwa.K[l * 4 + zz] = cfg[l].K; cwa.M[l * 4 + zz] = cfg[l].M;
    }
  }

  // prologue: cvt_w_all + fill(cntb) + fill(pooled+cnt) + cvt_split fused
  prologue<<<3200 + divup(N * 192, 256), blk, 0, stream>>>(
      cwa, Wh12, Wl12, x, Ah, Al, N * 192, cntb, N, (int*)pooled, B * 192 + B);

  hist_dst<<<divup(E, 256), blk, 0, stream>>>(dstp, cntb, E);
  scan_hist<<<1, dim3(1024), 0, stream>>>(cntb, startb, offb, N);
  scatter_edges<<<divup(E, 256), blk, 0, stream>>>(srcp, dstp, eattr, offb,
                                                  se, eid_s, E);

  // layers 0,1: gemm-s writes xb (read-only in fused attn); layer 2: xa (+=)
  float*       lay_out[3] = {xb, xb, xa};
  float*       alpha_out[3] = {a1, a2, a3};
  const float* gams[3] = {g1, g2, nullptr};
  const float* bets[3] = {be1, be2, nullptr};

  int stripes64 = divup(N, 64);
  for (int l = 0; l < 3; l++) {
    int M = cfg[l].M;
    GemmArgs ga;
    float* outs[4] = {(float*)qh, (float*)kh, (float*)vh, lay_out[l]};
    const float* biases[4] = {bq[l], bk[l], bv[l], bs[l]};
    int obfs[4] = {1, 1, 1, 0};
    for (int z = 0; z < 4; z++) {
      ga.Wh[z] = Wh12 + (size_t)(l * 4 + z) * 65536;
      ga.Wl[z] = Wl12 + (size_t)(l * 4 + z) * 65536;
      ga.bias[z] = biases[z];
      ga.out[z] = outs[z];
      ga.obf[z] = obfs[z];
    }
    dim3 gg((M >> 6) * 2 * stripes64);
    if (l == 0)      gemm2z_lds<192><<<gg, blk, 0, stream>>>(Ah, Al, ga, N, M);
    else             gemm2z_lds<256><<<gg, blk, 0, stream>>>(Ah, Al, ga, N, M);

    dim3 gat(divup(N * 64, 256));
    if (l < 2) {
      attn_fused<4, 32, 1><<<gat, blk, 0, stream>>>(
          qh, kh, vh, We[l], startb, se, eid_s, sc, lay_out[l],
          alpha_out[l], N, cfg[l].scale, gams[l], bets[l], Ah, Al);
    } else {
      attn_fused<6, 24, 0><<<gat, blk, 0, stream>>>(
          qh, kh, vh, We[l], startb, se, eid_s, sc, lay_out[l],
          alpha_out[l], N, cfg[l].scale, nullptr, nullptr, nullptr, nullptr);
    }
  }

  resid_pool2<<<divup(N, 32), dim3(192), 0, stream>>>(x, xa, batch, pooled, cnt, N, 32);
  head_mlp<<<B, dim3(64), 0, stream>>>(pooled, cnt, fc1w, fc1b, fc2w, fc2b, logits);
}